// Round 10
// baseline (317.150 us; speedup 1.0000x reference)
//
#include <hip/hip_runtime.h>

// Problem constants (B=16, DIM=256, H=W=56, NH=8, HD=32, WS=7)
#define BATCH 16
#define DIM 256
#define HH 56
#define WW 56
#define HWP 3136            // 56*56
#define M_TOT 50176         // BATCH*HWP
#define NQKV 768            // 3*DIM
#define NHEADS 8
#define HDIM 32
#define NWIN 49             // 7*7
// workspace offsets (bytes)
#define QKV_BYTES   77070336ull   // M_TOT*NQKV*2 (bf16)
#define XT_OFF      77070336ull
#define XT_BYTES    25690112ull   // M_TOT*DIM*2
#define WQT_OFF    102760448ull
#define PWB_OFF    103153664ull
#define FCONV_OFF  103284736ull   // bf16 fconv: 288*HWP*BATCH*2 = 28901376

typedef float f32x4 __attribute__((ext_vector_type(4)));
typedef short short8 __attribute__((ext_vector_type(8)));
typedef unsigned short ushort4v __attribute__((ext_vector_type(4)));

__device__ __forceinline__ short f2bf(float f) {
    unsigned u = __float_as_uint(f);
    u += 0x7fffu + ((u >> 16) & 1u);   // RNE
    return (short)(u >> 16);
}
__device__ __forceinline__ float bf2f(unsigned short u) {
    return __uint_as_float(((unsigned)u) << 16);
}
__device__ __forceinline__ unsigned pack2bf(float lo, float hi) {
    unsigned ul = __float_as_uint(lo); ul += 0x7fffu + ((ul >> 16) & 1u);
    unsigned uh = __float_as_uint(hi); uh += 0x7fffu + ((uh >> 16) & 1u);
    return (ul >> 16) | (uh & 0xffff0000u);
}
__device__ __forceinline__ int div7(int n) { return (n * 9363) >> 16; }  // exact for 0..63

// ---------------------------------------------------------------------------
// Kernel T0: x (B,C,HW) fp32 -> xt (B*HW, C) bf16.
__global__ __launch_bounds__(256) void xpose_kernel(const float* __restrict__ x,
                                                    unsigned short* __restrict__ xt) {
    __shared__ unsigned short tls[64 * 448];   // [ch][px'] swizzled, 56 KB
    const int tid = threadIdx.x;
    const int p0 = blockIdx.x * 448;
    const int k0 = blockIdx.y * 64;
    const int b  = blockIdx.z;
    const float* xb = x + ((size_t)b * DIM + k0) * HWP + p0;
    #pragma unroll
    for (int pass = 0; pass < 28; ++pass) {
        int idx = tid + pass * 256;            // float4 index (64*112 total)
        int ch = idx / 112, px4 = idx - ch * 112;
        float4 v = *(const float4*)(xb + (size_t)ch * HWP + px4 * 4);
        int px4s = px4 ^ ((ch >> 3) & 7);
        ushort4v s;
        s[0] = (unsigned short)f2bf(v.x); s[1] = (unsigned short)f2bf(v.y);
        s[2] = (unsigned short)f2bf(v.z); s[3] = (unsigned short)f2bf(v.w);
        *(ushort4v*)&tls[ch * 448 + px4s * 4] = s;
    }
    __syncthreads();
    unsigned short* xto = xt + ((size_t)b * HWP + p0) * DIM + k0;
    #pragma unroll
    for (int q = 0; q < 14; ++q) {
        int idx = tid + q * 256;               // uint4 index (3584 total)
        int px = idx >> 3, j8 = (idx & 7) * 8;
        int key = (j8 >> 3) & 7;
        int pxs = ((px >> 2) ^ key) * 4 + (px & 3);
        unsigned r[4];
        #pragma unroll
        for (int jj = 0; jj < 4; ++jj) {
            unsigned lo = tls[(j8 + 2 * jj) * 448 + pxs];
            unsigned hi = tls[(j8 + 2 * jj + 1) * 448 + pxs];
            r[jj] = lo | (hi << 16);
        }
        uint4 o; o.x = r[0]; o.y = r[1]; o.z = r[2]; o.w = r[3];
        *(uint4*)(xto + (size_t)px * DIM + j8) = o;
    }
}

// ---------------------------------------------------------------------------
// Kernel T1: blocks 0..47: wq (k,j) -> wqt (j,k) bf16; 48..63: proj_w cast.
__global__ __launch_bounds__(256) void prep_kernel(const float* __restrict__ wq,
                                                   const float* __restrict__ pw,
                                                   unsigned short* __restrict__ wqt,
                                                   unsigned short* __restrict__ pwb) {
    const int tid = threadIdx.x;
    const int bid = blockIdx.x;
    if (bid < 48) {
        __shared__ float t[64][65];
        const int j0 = (bid >> 2) * 64, k0 = (bid & 3) * 64;
        #pragma unroll
        for (int kk = tid >> 6; kk < 64; kk += 4)
            t[kk][tid & 63] = wq[(size_t)(k0 + kk) * NQKV + j0 + (tid & 63)];
        __syncthreads();
        const int jj = tid >> 2, c16 = (tid & 3) * 16;
        unsigned short* dst = wqt + (size_t)(j0 + jj) * DIM + k0 + c16;
        #pragma unroll
        for (int i = 0; i < 16; ++i) dst[i] = (unsigned short)f2bf(t[c16 + i][jj]);
    } else {
        const int base = (bid - 48) * 4096 + tid;
        #pragma unroll
        for (int i = 0; i < 16; ++i)
            pwb[base + i * 256] = (unsigned short)f2bf(pw[base + i * 256]);
    }
}

// ---------------------------------------------------------------------------
// Kernel A (MFMA): qkv[m][j] = sum_k xt[m][k] * wqt[j][k] + bq[j]  (bf16 out)
__global__ __launch_bounds__(256) void qkv_gemm(const unsigned short* __restrict__ xt,
                                                const unsigned short* __restrict__ wqt,
                                                const float* __restrict__ bq,
                                                unsigned short* __restrict__ qkv) {
    __shared__ short A_lds[128 * 64];
    __shared__ short B_lds[128 * 64];
    const int bidx = blockIdx.x;
    const int wg = (bidx & 7) * 294 + (bidx >> 3);
    const int jt = wg % 6, mt = wg / 6;
    const int m0 = mt * 128, j0 = jt * 128;

    const int tid = threadIdx.x;
    const int lane = tid & 63;
    const int wave = tid >> 6;
    const int wr = wave >> 1, wc = wave & 1;

    const int srow = tid & 127;
    const int kh = tid >> 7;
    const unsigned short* aptr = xt  + (size_t)(m0 + srow) * DIM + kh * 32;
    const unsigned short* bptr = wqt + (size_t)(j0 + srow) * DIM + kh * 32;

    f32x4 acc[4][4];
    #pragma unroll
    for (int i = 0; i < 4; ++i)
        #pragma unroll
        for (int j = 0; j < 4; ++j) acc[i][j] = (f32x4){0.f, 0.f, 0.f, 0.f};

    const int r = lane & 15, q = lane >> 4;
    for (int k0 = 0; k0 < DIM; k0 += 64) {
        __syncthreads();
        #pragma unroll
        for (int g = 0; g < 4; ++g) {
            *(short8*)&A_lds[srow * 64 + 8 * ((kh * 4 + g) ^ (srow & 7))] =
                *(const short8*)(aptr + k0 + g * 8);
            *(short8*)&B_lds[srow * 64 + 8 * ((kh * 4 + g) ^ (srow & 7))] =
                *(const short8*)(bptr + k0 + g * 8);
        }
        __syncthreads();
        #pragma unroll
        for (int ks = 0; ks < 2; ++ks) {
            short8 af[4], bfr[4];
            #pragma unroll
            for (int f = 0; f < 4; ++f) {
                int mrow = wr * 64 + f * 16 + r;
                af[f] = *(const short8*)&A_lds[mrow * 64 + 8 * ((ks * 4 + q) ^ (mrow & 7))];
                int nrow = wc * 64 + f * 16 + r;
                bfr[f] = *(const short8*)&B_lds[nrow * 64 + 8 * ((ks * 4 + q) ^ (nrow & 7))];
            }
            #pragma unroll
            for (int fm = 0; fm < 4; ++fm)
                #pragma unroll
                for (int fj = 0; fj < 4; ++fj)
                    acc[fm][fj] = __builtin_amdgcn_mfma_f32_16x16x32_bf16(
                        af[fm], bfr[fj], acc[fm][fj], 0, 0, 0);
        }
    }
    #pragma unroll
    for (int fm = 0; fm < 4; ++fm) {
        const int mbase = m0 + wr * 64 + fm * 16 + q * 4;
        #pragma unroll
        for (int fj = 0; fj < 4; ++fj) {
            const int j = j0 + wc * 64 + fj * 16 + r;
            const float bias = bq[j];
            unsigned short* op = qkv + (size_t)mbase * NQKV + j;
            #pragma unroll
            for (int rg = 0; rg < 4; ++rg)
                op[(size_t)rg * NQKV] = (unsigned short)f2bf(acc[fm][fj][rg] + bias);
        }
    }
}

// ---------------------------------------------------------------------------
// Kernel B: f_conv[b, g*9+o, p] = sum_c fc_w[o,c]*bf2f(qkv[b,p,c*32+g]) + fc_b[o]
__global__ __launch_bounds__(256) void fc_kernel(const unsigned short* __restrict__ qkv,
                                                 const float* __restrict__ fc_w,
                                                 const float* __restrict__ fc_b,
                                                 unsigned short* __restrict__ fconv) {
    __shared__ unsigned short f[16 * 768];   // 24 KB
    __shared__ float ob[16][289];
    __shared__ float w[9][24];
    __shared__ float bsh[9];
    const int tid = threadIdx.x;
    if (tid < 216) w[tid / 24][tid % 24] = fc_w[tid];
    if (tid < 9) bsh[tid] = fc_b[tid];
    const int p0 = blockIdx.x * 16;
    const int b  = blockIdx.y;
    const uint4* src = (const uint4*)(qkv + ((size_t)b * HWP + p0) * NQKV);
    uint4* dstf = (uint4*)f;
    #pragma unroll
    for (int i = 0; i < 6; ++i) dstf[tid + i * 256] = src[tid + i * 256];
    __syncthreads();
    #pragma unroll
    for (int it = 0; it < 2; ++it) {
        const int item = tid + it * 256;
        const int pp = item >> 5, g = item & 31;
        const unsigned short* fr = f + pp * 768 + g;
        float acc[9];
        #pragma unroll
        for (int o = 0; o < 9; ++o) acc[o] = bsh[o];
        #pragma unroll
        for (int c = 0; c < 24; ++c) {
            float v = bf2f(fr[c * 32]);
            #pragma unroll
            for (int o = 0; o < 9; ++o) acc[o] += w[o][c] * v;
        }
        #pragma unroll
        for (int o = 0; o < 9; ++o) ob[pp][g * 9 + o] = acc[o];
    }
    __syncthreads();
    unsigned short* og = fconv + (size_t)b * 288 * HWP + p0;
    for (int i = tid; i < 288 * 16; i += 256) {
        int ch = i >> 4, pp = i & 15;
        og[(size_t)ch * HWP + pp] = (unsigned short)f2bf(ob[pp][ch]);
    }
}

// ---------------------------------------------------------------------------
// Kernel C (v3): grouped 3x3 conv. Block = (28x28 tile, g, b).
// bf16 LDS halo [9][30][36] (19.4 KB -> 7 blocks/CU; stride 36 kills the
// bank-wrap conflicts of v2), b64+b32 tap reads + 1-op bf16 unpack.
__global__ __launch_bounds__(256) void conv_kernel(const unsigned short* __restrict__ fconv,
                                                   const float* __restrict__ dep_w,
                                                   const float* __restrict__ rate2p,
                                                   float* __restrict__ out) {
    __shared__ unsigned short hal[9][30][36];  // 19440 B
    __shared__ float wfl[81][8];               // [o*9+kidx][c8]
    const int tid = threadIdx.x;
    const int t = blockIdx.x;                  // 4 tiles of 28x28
    const int ty0 = (t >> 1) * 28, tx0 = (t & 1) * 28;
    const int g = blockIdx.y, b = blockIdx.z;

    for (int i = tid; i < 648; i += 256) {
        int ok = i >> 3, c8 = i & 7;
        wfl[ok][c8] = dep_w[(size_t)(g * 8 + c8) * 81 + ok];
    }
    const unsigned short* fp = fconv + ((size_t)b * 288 + g * 9) * HWP;
    for (int i = tid; i < 8100; i += 256) {
        int o = i / 900, rem = i - o * 900;
        int y = rem / 30, xx = rem - y * 30;
        int yy = ty0 - 1 + y, xi = tx0 - 1 + xx;
        unsigned short v = 0;
        if (yy >= 0 && yy < HH && xi >= 0 && xi < WW)
            v = fp[(size_t)o * HWP + yy * WW + xi];
        hal[o][y][xx] = v;
    }
    __syncthreads();
    if (tid < 196) {
        const int oy = tid / 7, xq = tid - oy * 7;   // 28 rows x 7 quads
        const int x0 = xq * 4;
        float acc[8][4] = {};
        #pragma unroll
        for (int o = 0; o < 9; ++o) {
            #pragma unroll
            for (int ky = 0; ky < 3; ++ky) {
                const unsigned short* hrow = &hal[o][oy + ky][x0];
                uint2 u0 = *(const uint2*)hrow;          // x0..x0+3
                unsigned u1 = *(const unsigned*)(hrow + 4); // x0+4, x0+5
                float v[6];
                v[0] = __uint_as_float(u0.x << 16);
                v[1] = __uint_as_float(u0.x & 0xffff0000u);
                v[2] = __uint_as_float(u0.y << 16);
                v[3] = __uint_as_float(u0.y & 0xffff0000u);
                v[4] = __uint_as_float(u1 << 16);
                v[5] = __uint_as_float(u1 & 0xffff0000u);
                #pragma unroll
                for (int kx = 0; kx < 3; ++kx) {
                    f32x4 w0 = *(const f32x4*)&wfl[o * 9 + ky * 3 + kx][0];
                    f32x4 w1 = *(const f32x4*)&wfl[o * 9 + ky * 3 + kx][4];
                    #pragma unroll
                    for (int j = 0; j < 4; ++j) {
                        const float vv = v[j + kx];
                        acc[0][j] += vv * w0[0]; acc[1][j] += vv * w0[1];
                        acc[2][j] += vv * w0[2]; acc[3][j] += vv * w0[3];
                        acc[4][j] += vv * w1[0]; acc[5][j] += vv * w1[1];
                        acc[6][j] += vv * w1[2]; acc[7][j] += vv * w1[3];
                    }
                }
            }
        }
        const float r2 = rate2p[0];
        const int y = ty0 + oy, xg = tx0 + x0;
        #pragma unroll
        for (int c8 = 0; c8 < 8; ++c8) {
            float4 s;
            s.x = r2 * acc[c8][0]; s.y = r2 * acc[c8][1];
            s.z = r2 * acc[c8][2]; s.w = r2 * acc[c8][3];
            *(float4*)&out[((size_t)b * DIM + g * 8 + c8) * HWP + y * WW + xg] = s;
        }
    }
}

// ---------------------------------------------------------------------------
// Kernel D (MFMA flash-style): one block = one window, 8 waves = 8 heads.
__global__ __launch_bounds__(512) void attn_kernel(const unsigned short* __restrict__ qkv,
                                                   const float* __restrict__ rpb,
                                                   unsigned short* __restrict__ obuf) {
    __shared__ __attribute__((aligned(16))) short VT[256 * 72];  // [h*32+d][m] 36 KB
    __shared__ __attribute__((aligned(16))) short PL[8 * 16 * 72]; // per-wave [16][72] 18 KB
    const int tid = threadIdx.x;
    const int win = blockIdx.x;
    const int b = win >> 6, wrw = win & 63;
    const int wy = wrw >> 3, wx = wrw & 7;
    const size_t wbase = (size_t)b * HWP + (size_t)(wy * 7) * WW + wx * 7;

    {
        const int m = tid & 63;
        const int mq = div7(m), mr = m - mq * 7;
        const unsigned short* vrow = qkv + (wbase + mq * WW + mr) * NQKV + 512;
        for (int R = tid >> 6; R < 256; R += 8)
            VT[R * 72 + m] = (m < 49) ? (short)vrow[R] : (short)0;
    }

    const int lane = tid & 63;
    const int h = tid >> 6;
    const int c = lane & 15, qg = lane >> 4;

    short8 aq[4], bk[4];
    #pragma unroll
    for (int f = 0; f < 4; ++f) {
        int t = f * 16 + c; if (t > 48) t = 48;
        const int tq = div7(t), tr = t - tq * 7;
        const unsigned short* base = qkv + (wbase + tq * WW + tr) * NQKV + h * 32 + qg * 8;
        aq[f] = *(const short8*)base;
        bk[f] = *(const short8*)(base + 256);
    }
    __syncthreads();

    short8 bv[2][2];
    #pragma unroll
    for (int ks = 0; ks < 2; ++ks)
        #pragma unroll
        for (int fo = 0; fo < 2; ++fo)
            bv[ks][fo] = *(const short8*)&VT[(h * 32 + fo * 16 + c) * 72 + ks * 32 + qg * 8];

    const float scale = 0.17677669529663687f;
    short* pw = PL + h * 16 * 72;

    #pragma unroll
    for (int fm = 0; fm < 4; ++fm) {
        f32x4 s[4];
        #pragma unroll
        for (int fj = 0; fj < 4; ++fj)
            s[fj] = __builtin_amdgcn_mfma_f32_16x16x32_bf16(aq[fm], bk[fj],
                                                            (f32x4){0.f,0.f,0.f,0.f}, 0, 0, 0);
        float p[4][4];
        #pragma unroll
        for (int reg = 0; reg < 4; ++reg) {
            int n = fm * 16 + qg * 4 + reg; int nc = n > 48 ? 48 : n;
            int nd = div7(nc), nm = nc - nd * 7;
            #pragma unroll
            for (int fj = 0; fj < 4; ++fj) {
                int mm = fj * 16 + c;
                float bias;
                if (mm < 49) {
                    int md = div7(mm), mmod = mm - md * 7;
                    int idx = (nd - md + 6) * 13 + (nm - mmod + 6);
                    bias = rpb[idx * NHEADS + h];
                } else bias = -1e30f;
                p[fj][reg] = s[fj][reg] * scale + bias;
            }
        }
        float inv[4];
        #pragma unroll
        for (int reg = 0; reg < 4; ++reg) {
            float mx = fmaxf(fmaxf(p[0][reg], p[1][reg]), fmaxf(p[2][reg], p[3][reg]));
            mx = fmaxf(mx, __shfl_xor(mx, 1));
            mx = fmaxf(mx, __shfl_xor(mx, 2));
            mx = fmaxf(mx, __shfl_xor(mx, 4));
            mx = fmaxf(mx, __shfl_xor(mx, 8));
            float sum = 0.f;
            #pragma unroll
            for (int fj = 0; fj < 4; ++fj) {
                float e = __expf(p[fj][reg] - mx);
                p[fj][reg] = e; sum += e;
            }
            sum += __shfl_xor(sum, 1);
            sum += __shfl_xor(sum, 2);
            sum += __shfl_xor(sum, 4);
            sum += __shfl_xor(sum, 8);
            inv[reg] = 1.0f / sum;
        }
        #pragma unroll
        for (int fj = 0; fj < 4; ++fj)
            #pragma unroll
            for (int reg = 0; reg < 4; ++reg) {
                float v = p[fj][reg] * inv[reg];
                float o = __shfl_xor(v, 1);
                unsigned packed = (c & 1) ? pack2bf(o, v) : pack2bf(v, o);
                if ((c & 1) == 0)
                    *(unsigned*)&pw[(qg * 4 + reg) * 72 + fj * 16 + c] = packed;
            }
        short8 ap0 = *(const short8*)&pw[c * 72 + 0 * 32 + qg * 8];
        short8 ap1 = *(const short8*)&pw[c * 72 + 1 * 32 + qg * 8];
        #pragma unroll
        for (int fo = 0; fo < 2; ++fo) {
            f32x4 o4 = __builtin_amdgcn_mfma_f32_16x16x32_bf16(ap0, bv[0][fo],
                                                               (f32x4){0.f,0.f,0.f,0.f}, 0, 0, 0);
            o4 = __builtin_amdgcn_mfma_f32_16x16x32_bf16(ap1, bv[1][fo], o4, 0, 0, 0);
            #pragma unroll
            for (int reg = 0; reg < 4; ++reg) {
                int n = fm * 16 + qg * 4 + reg;
                if (n < 49) {
                    int nd = div7(n), nm = n - nd * 7;
                    obuf[(wbase + nd * WW + nm) * DIM + h * 32 + fo * 16 + c] =
                        (unsigned short)f2bf(o4[reg]);
                }
            }
        }
    }
}

// ---------------------------------------------------------------------------
// Kernel E (MFMA): out[b,c,p] += rate1 * (obuf @ proj_w^T + pb)
__global__ __launch_bounds__(256) void proj_gemm(const unsigned short* __restrict__ obuf,
                                                 const unsigned short* __restrict__ pwb,
                                                 const float* __restrict__ pb,
                                                 const float* __restrict__ rate1p,
                                                 float* __restrict__ out) {
    __shared__ short M_lds[128 * 64];
    __shared__ short C_lds[128 * 64];
    const int bidx = blockIdx.x;
    const int wg = (bidx & 7) * 98 + (bidx >> 3);   // grid 784 = 8*98
    const int ct = wg & 1, mt = wg >> 1;
    const int m0 = mt * 128, c0 = ct * 128;

    const int tid = threadIdx.x;
    const int lane = tid & 63;
    const int wave = tid >> 6;
    const int wr = wave >> 1, wc = wave & 1;

    const int srow = tid & 127;
    const int kh = tid >> 7;
    const unsigned short* mptr = obuf + (size_t)(m0 + srow) * DIM + kh * 32;
    const unsigned short* cptr = pwb  + (size_t)(c0 + srow) * DIM + kh * 32;

    f32x4 acc[4][4];
    #pragma unroll
    for (int i = 0; i < 4; ++i)
        #pragma unroll
        for (int j = 0; j < 4; ++j) acc[i][j] = (f32x4){0.f, 0.f, 0.f, 0.f};

    const int r = lane & 15, q = lane >> 4;
    for (int k0 = 0; k0 < DIM; k0 += 64) {
        __syncthreads();
        #pragma unroll
        for (int g = 0; g < 4; ++g) {
            *(short8*)&M_lds[srow * 64 + 8 * ((kh * 4 + g) ^ (srow & 7))] =
                *(const short8*)(mptr + k0 + g * 8);
            *(short8*)&C_lds[srow * 64 + 8 * ((kh * 4 + g) ^ (srow & 7))] =
                *(const short8*)(cptr + k0 + g * 8);
        }
        __syncthreads();
        #pragma unroll
        for (int ks = 0; ks < 2; ++ks) {
            short8 cf[4], mf[4];
            #pragma unroll
            for (int f = 0; f < 4; ++f) {
                int crow = wr * 64 + f * 16 + r;
                cf[f] = *(const short8*)&C_lds[crow * 64 + 8 * ((ks * 4 + q) ^ (crow & 7))];
                int mrow = wc * 64 + f * 16 + r;
                mf[f] = *(const short8*)&M_lds[mrow * 64 + 8 * ((ks * 4 + q) ^ (mrow & 7))];
            }
            #pragma unroll
            for (int fc = 0; fc < 4; ++fc)
                #pragma unroll
                for (int fm2 = 0; fm2 < 4; ++fm2)
                    acc[fc][fm2] = __builtin_amdgcn_mfma_f32_16x16x32_bf16(
                        cf[fc], mf[fm2], acc[fc][fm2], 0, 0, 0);
        }
    }
    const float r1 = rate1p[0];
    size_t boff[4];
    #pragma unroll
    for (int fm2 = 0; fm2 < 4; ++fm2) {
        int mb = m0 + wc * 64 + fm2 * 16 + r;
        boff[fm2] = (size_t)(mb / HWP) * DIM * HWP + (mb % HWP);
    }
    #pragma unroll
    for (int fc = 0; fc < 4; ++fc) {
        #pragma unroll
        for (int reg = 0; reg < 4; ++reg) {
            const int cc = c0 + wr * 64 + fc * 16 + q * 4 + reg;
            const float bias = pb[cc];
            #pragma unroll
            for (int fm2 = 0; fm2 < 4; ++fm2) {
                float* dst = out + boff[fm2] + (size_t)cc * HWP;
                *dst = *dst + r1 * (acc[fc][fm2][reg] + bias);
            }
        }
    }
}

// ---------------------------------------------------------------------------
extern "C" void kernel_launch(void* const* d_in, const int* in_sizes, int n_in,
                              void* d_out, int out_size, void* d_ws, size_t ws_size,
                              hipStream_t stream) {
    const float* x      = (const float*)d_in[0];
    const float* qkv_w  = (const float*)d_in[1];
    const float* qkv_b  = (const float*)d_in[2];
    const float* fc_w   = (const float*)d_in[3];
    const float* fc_b   = (const float*)d_in[4];
    const float* dep_w  = (const float*)d_in[5];
    const float* proj_w = (const float*)d_in[6];
    const float* proj_b = (const float*)d_in[7];
    const float* rpb    = (const float*)d_in[8];
    const float* rate1  = (const float*)d_in[9];
    const float* rate2  = (const float*)d_in[10];
    float* out = (float*)d_out;

    unsigned short* qkv   = (unsigned short*)d_ws;
    unsigned short* xt    = (unsigned short*)((char*)d_ws + XT_OFF);
    unsigned short* wqt   = (unsigned short*)((char*)d_ws + WQT_OFF);
    unsigned short* pwb   = (unsigned short*)((char*)d_ws + PWB_OFF);
    unsigned short* fconv = (unsigned short*)((char*)d_ws + FCONV_OFF);
    unsigned short* obuf  = fconv;  // reused after conv_kernel consumes fconv

    xpose_kernel<<<dim3(7, 4, BATCH), 256, 0, stream>>>(x, xt);
    prep_kernel<<<dim3(64), 256, 0, stream>>>(qkv_w, proj_w, wqt, pwb);
    qkv_gemm<<<dim3(2352), 256, 0, stream>>>(xt, wqt, qkv_b, qkv);
    fc_kernel<<<dim3(HWP / 16, BATCH), 256, 0, stream>>>(qkv, fc_w, fc_b, fconv);
    conv_kernel<<<dim3(4, 32, BATCH), 256, 0, stream>>>(fconv, dep_w, rate2, out);
    attn_kernel<<<dim3(1024), 512, 0, stream>>>(qkv, rpb, obuf);
    proj_gemm<<<dim3(784), 256, 0, stream>>>(obuf, pwb, proj_b, rate1, out);
}

// Round 11
// 284.938 us; speedup vs baseline: 1.1130x; 1.1130x over previous
//
#include <hip/hip_runtime.h>

// Problem constants (B=16, DIM=256, H=W=56, NH=8, HD=32, WS=7)
#define BATCH 16
#define DIM 256
#define HH 56
#define WW 56
#define HWP 3136            // 56*56
#define M_TOT 50176         // BATCH*HWP
#define NQKV 768            // 3*DIM
#define NHEADS 8
#define HDIM 32
#define NWIN 49             // 7*7
// workspace offsets (bytes)
#define QKV_BYTES   77070336ull   // M_TOT*NQKV*2 (bf16)
#define XT_OFF      77070336ull
#define XT_BYTES    25690112ull   // M_TOT*DIM*2
#define WQT_OFF    102760448ull
#define PWB_OFF    103153664ull
#define FCONV_OFF  103284736ull   // bf16 fconv: 288*HWP*BATCH*2 = 28901376

typedef float f32x4 __attribute__((ext_vector_type(4)));
typedef short short8 __attribute__((ext_vector_type(8)));
typedef unsigned short ushort4v __attribute__((ext_vector_type(4)));

__device__ __forceinline__ short f2bf(float f) {
    unsigned u = __float_as_uint(f);
    u += 0x7fffu + ((u >> 16) & 1u);   // RNE
    return (short)(u >> 16);
}
__device__ __forceinline__ float bf2f(unsigned short u) {
    return __uint_as_float(((unsigned)u) << 16);
}
__device__ __forceinline__ unsigned pack2bf(float lo, float hi) {
    unsigned ul = __float_as_uint(lo); ul += 0x7fffu + ((ul >> 16) & 1u);
    unsigned uh = __float_as_uint(hi); uh += 0x7fffu + ((uh >> 16) & 1u);
    return (ul >> 16) | (uh & 0xffff0000u);
}
__device__ __forceinline__ int div7(int n) { return (n * 9363) >> 16; }  // exact for 0..63

// ---------------------------------------------------------------------------
// Kernel T0: x (B,C,HW) fp32 -> xt (B*HW, C) bf16.
__global__ __launch_bounds__(256) void xpose_kernel(const float* __restrict__ x,
                                                    unsigned short* __restrict__ xt) {
    __shared__ unsigned short tls[64 * 448];   // [ch][px'] swizzled, 56 KB
    const int tid = threadIdx.x;
    const int p0 = blockIdx.x * 448;
    const int k0 = blockIdx.y * 64;
    const int b  = blockIdx.z;
    const float* xb = x + ((size_t)b * DIM + k0) * HWP + p0;
    #pragma unroll
    for (int pass = 0; pass < 28; ++pass) {
        int idx = tid + pass * 256;            // float4 index (64*112 total)
        int ch = idx / 112, px4 = idx - ch * 112;
        float4 v = *(const float4*)(xb + (size_t)ch * HWP + px4 * 4);
        int px4s = px4 ^ ((ch >> 3) & 7);
        ushort4v s;
        s[0] = (unsigned short)f2bf(v.x); s[1] = (unsigned short)f2bf(v.y);
        s[2] = (unsigned short)f2bf(v.z); s[3] = (unsigned short)f2bf(v.w);
        *(ushort4v*)&tls[ch * 448 + px4s * 4] = s;
    }
    __syncthreads();
    unsigned short* xto = xt + ((size_t)b * HWP + p0) * DIM + k0;
    #pragma unroll
    for (int q = 0; q < 14; ++q) {
        int idx = tid + q * 256;               // uint4 index (3584 total)
        int px = idx >> 3, j8 = (idx & 7) * 8;
        int key = (j8 >> 3) & 7;
        int pxs = ((px >> 2) ^ key) * 4 + (px & 3);
        unsigned r[4];
        #pragma unroll
        for (int jj = 0; jj < 4; ++jj) {
            unsigned lo = tls[(j8 + 2 * jj) * 448 + pxs];
            unsigned hi = tls[(j8 + 2 * jj + 1) * 448 + pxs];
            r[jj] = lo | (hi << 16);
        }
        uint4 o; o.x = r[0]; o.y = r[1]; o.z = r[2]; o.w = r[3];
        *(uint4*)(xto + (size_t)px * DIM + j8) = o;
    }
}

// ---------------------------------------------------------------------------
// Kernel T1: blocks 0..47: wq (k,j) -> wqt (j,k) bf16; 48..63: proj_w cast.
__global__ __launch_bounds__(256) void prep_kernel(const float* __restrict__ wq,
                                                   const float* __restrict__ pw,
                                                   unsigned short* __restrict__ wqt,
                                                   unsigned short* __restrict__ pwb) {
    const int tid = threadIdx.x;
    const int bid = blockIdx.x;
    if (bid < 48) {
        __shared__ float t[64][65];
        const int j0 = (bid >> 2) * 64, k0 = (bid & 3) * 64;
        #pragma unroll
        for (int kk = tid >> 6; kk < 64; kk += 4)
            t[kk][tid & 63] = wq[(size_t)(k0 + kk) * NQKV + j0 + (tid & 63)];
        __syncthreads();
        const int jj = tid >> 2, c16 = (tid & 3) * 16;
        unsigned short* dst = wqt + (size_t)(j0 + jj) * DIM + k0 + c16;
        #pragma unroll
        for (int i = 0; i < 16; ++i) dst[i] = (unsigned short)f2bf(t[c16 + i][jj]);
    } else {
        const int base = (bid - 48) * 4096 + tid;
        #pragma unroll
        for (int i = 0; i < 16; ++i)
            pwb[base + i * 256] = (unsigned short)f2bf(pw[base + i * 256]);
    }
}

// ---------------------------------------------------------------------------
// Kernel A (MFMA): qkv[m][j] = sum_k xt[m][k] * wqt[j][k] + bq[j]  (bf16 out)
__global__ __launch_bounds__(256) void qkv_gemm(const unsigned short* __restrict__ xt,
                                                const unsigned short* __restrict__ wqt,
                                                const float* __restrict__ bq,
                                                unsigned short* __restrict__ qkv) {
    __shared__ short A_lds[128 * 64];
    __shared__ short B_lds[128 * 64];
    const int bidx = blockIdx.x;
    const int wg = (bidx & 7) * 294 + (bidx >> 3);
    const int jt = wg % 6, mt = wg / 6;
    const int m0 = mt * 128, j0 = jt * 128;

    const int tid = threadIdx.x;
    const int lane = tid & 63;
    const int wave = tid >> 6;
    const int wr = wave >> 1, wc = wave & 1;

    const int srow = tid & 127;
    const int kh = tid >> 7;
    const unsigned short* aptr = xt  + (size_t)(m0 + srow) * DIM + kh * 32;
    const unsigned short* bptr = wqt + (size_t)(j0 + srow) * DIM + kh * 32;

    f32x4 acc[4][4];
    #pragma unroll
    for (int i = 0; i < 4; ++i)
        #pragma unroll
        for (int j = 0; j < 4; ++j) acc[i][j] = (f32x4){0.f, 0.f, 0.f, 0.f};

    const int r = lane & 15, q = lane >> 4;
    for (int k0 = 0; k0 < DIM; k0 += 64) {
        __syncthreads();
        #pragma unroll
        for (int g = 0; g < 4; ++g) {
            *(short8*)&A_lds[srow * 64 + 8 * ((kh * 4 + g) ^ (srow & 7))] =
                *(const short8*)(aptr + k0 + g * 8);
            *(short8*)&B_lds[srow * 64 + 8 * ((kh * 4 + g) ^ (srow & 7))] =
                *(const short8*)(bptr + k0 + g * 8);
        }
        __syncthreads();
        #pragma unroll
        for (int ks = 0; ks < 2; ++ks) {
            short8 af[4], bfr[4];
            #pragma unroll
            for (int f = 0; f < 4; ++f) {
                int mrow = wr * 64 + f * 16 + r;
                af[f] = *(const short8*)&A_lds[mrow * 64 + 8 * ((ks * 4 + q) ^ (mrow & 7))];
                int nrow = wc * 64 + f * 16 + r;
                bfr[f] = *(const short8*)&B_lds[nrow * 64 + 8 * ((ks * 4 + q) ^ (nrow & 7))];
            }
            #pragma unroll
            for (int fm = 0; fm < 4; ++fm)
                #pragma unroll
                for (int fj = 0; fj < 4; ++fj)
                    acc[fm][fj] = __builtin_amdgcn_mfma_f32_16x16x32_bf16(
                        af[fm], bfr[fj], acc[fm][fj], 0, 0, 0);
        }
    }
    #pragma unroll
    for (int fm = 0; fm < 4; ++fm) {
        const int mbase = m0 + wr * 64 + fm * 16 + q * 4;
        #pragma unroll
        for (int fj = 0; fj < 4; ++fj) {
            const int j = j0 + wc * 64 + fj * 16 + r;
            const float bias = bq[j];
            unsigned short* op = qkv + (size_t)mbase * NQKV + j;
            #pragma unroll
            for (int rg = 0; rg < 4; ++rg)
                op[(size_t)rg * NQKV] = (unsigned short)f2bf(acc[fm][fj][rg] + bias);
        }
    }
}

// ---------------------------------------------------------------------------
// Kernel B: f_conv[b, g*9+o, p] = sum_c fc_w[o,c]*bf2f(qkv[b,p,c*32+g]) + fc_b[o]
__global__ __launch_bounds__(256) void fc_kernel(const unsigned short* __restrict__ qkv,
                                                 const float* __restrict__ fc_w,
                                                 const float* __restrict__ fc_b,
                                                 unsigned short* __restrict__ fconv) {
    __shared__ unsigned short f[16 * 768];   // 24 KB
    __shared__ float ob[16][289];
    __shared__ float w[9][24];
    __shared__ float bsh[9];
    const int tid = threadIdx.x;
    if (tid < 216) w[tid / 24][tid % 24] = fc_w[tid];
    if (tid < 9) bsh[tid] = fc_b[tid];
    const int p0 = blockIdx.x * 16;
    const int b  = blockIdx.y;
    const uint4* src = (const uint4*)(qkv + ((size_t)b * HWP + p0) * NQKV);
    uint4* dstf = (uint4*)f;
    #pragma unroll
    for (int i = 0; i < 6; ++i) dstf[tid + i * 256] = src[tid + i * 256];
    __syncthreads();
    #pragma unroll
    for (int it = 0; it < 2; ++it) {
        const int item = tid + it * 256;
        const int pp = item >> 5, g = item & 31;
        const unsigned short* fr = f + pp * 768 + g;
        float acc[9];
        #pragma unroll
        for (int o = 0; o < 9; ++o) acc[o] = bsh[o];
        #pragma unroll
        for (int c = 0; c < 24; ++c) {
            float v = bf2f(fr[c * 32]);
            #pragma unroll
            for (int o = 0; o < 9; ++o) acc[o] += w[o][c] * v;
        }
        #pragma unroll
        for (int o = 0; o < 9; ++o) ob[pp][g * 9 + o] = acc[o];
    }
    __syncthreads();
    unsigned short* og = fconv + (size_t)b * 288 * HWP + p0;
    for (int i = tid; i < 288 * 16; i += 256) {
        int ch = i >> 4, pp = i & 15;
        og[(size_t)ch * HWP + pp] = (unsigned short)f2bf(ob[pp][ch]);
    }
}

// ---------------------------------------------------------------------------
// Kernel C (v4): grouped 3x3 conv, lane = output column.
// Block = (8-row strip, g, b). Halo [9][10][64] bf16 (11.5 KB). Tap reads are
// dword-broadcast pairs -> zero bank conflicts. All 4 waves compute (2 rows
// x 8 ch each). Writes rate2*conv to d_out (NCHW), coalesced.
__global__ __launch_bounds__(256) void conv_kernel(const unsigned short* __restrict__ fconv,
                                                   const float* __restrict__ dep_w,
                                                   const float* __restrict__ rate2p,
                                                   float* __restrict__ out) {
    __shared__ unsigned short hal[9][10][64];  // 11520 B
    __shared__ float wfl[81][8];               // [o*9+ky*3+kx][c8]
    const int tid = threadIdx.x;
    const int strip = blockIdx.x;              // 0..6 (8 rows each)
    const int g = blockIdx.y, b = blockIdx.z;

    for (int i = tid; i < 648; i += 256) {
        int ok = i >> 3, c8 = i & 7;
        wfl[ok][c8] = dep_w[(size_t)(g * 8 + c8) * 81 + ok];
    }
    const unsigned short* fp = fconv + ((size_t)b * 288 + g * 9) * HWP;
    const int y0 = strip * 8 - 1;
    for (int i = tid; i < 5760; i += 256) {
        int col = i & 63;
        int rest = i >> 6;                     // 0..89
        int o = rest / 10, y = rest - o * 10;
        int gy = y0 + y, gx = col - 1;
        unsigned short v = 0;
        if (gy >= 0 && gy < HH && (unsigned)gx < WW)
            v = fp[(size_t)o * HWP + gy * WW + gx];
        hal[o][y][col] = v;
    }
    __syncthreads();

    const int x = tid & 63;
    const int w = tid >> 6;                    // wave -> out rows 2w, 2w+1
    const int e = x & ~1;
    const bool odd = (x & 1) != 0;
    float acc[2][8] = {};
    for (int o = 0; o < 9; ++o) {
        float V[4][3];
        #pragma unroll
        for (int h = 0; h < 4; ++h) {
            const unsigned short* hr = &hal[o][2 * w + h][e];
            unsigned D0 = *(const unsigned*)hr;
            unsigned D1 = *(const unsigned*)(hr + 2);
            float a0 = __uint_as_float(D0 << 16);
            float a1 = __uint_as_float(D0 & 0xffff0000u);
            float a2 = __uint_as_float(D1 << 16);
            float a3 = __uint_as_float(D1 & 0xffff0000u);
            V[h][0] = odd ? a1 : a0;
            V[h][1] = odd ? a2 : a1;
            V[h][2] = odd ? a3 : a2;
        }
        #pragma unroll
        for (int ky = 0; ky < 3; ++ky)
            #pragma unroll
            for (int kx = 0; kx < 3; ++kx) {
                f32x4 w0 = *(const f32x4*)&wfl[o * 9 + ky * 3 + kx][0];
                f32x4 w1 = *(const f32x4*)&wfl[o * 9 + ky * 3 + kx][4];
                #pragma unroll
                for (int j = 0; j < 2; ++j) {
                    const float vv = V[j + ky][kx];
                    acc[j][0] += vv * w0[0]; acc[j][1] += vv * w0[1];
                    acc[j][2] += vv * w0[2]; acc[j][3] += vv * w0[3];
                    acc[j][4] += vv * w1[0]; acc[j][5] += vv * w1[1];
                    acc[j][6] += vv * w1[2]; acc[j][7] += vv * w1[3];
                }
            }
    }
    if (x < WW) {
        const float r2 = rate2p[0];
        #pragma unroll
        for (int j = 0; j < 2; ++j) {
            const int y = strip * 8 + 2 * w + j;
            #pragma unroll
            for (int c8 = 0; c8 < 8; ++c8)
                out[((size_t)b * DIM + g * 8 + c8) * HWP + y * WW + x] = r2 * acc[j][c8];
        }
    }
}

// ---------------------------------------------------------------------------
// Kernel D (MFMA flash-style): one block = one window, 8 waves = 8 heads.
__global__ __launch_bounds__(512) void attn_kernel(const unsigned short* __restrict__ qkv,
                                                   const float* __restrict__ rpb,
                                                   unsigned short* __restrict__ obuf) {
    __shared__ __attribute__((aligned(16))) short VT[256 * 72];  // [h*32+d][m] 36 KB
    __shared__ __attribute__((aligned(16))) short PL[8 * 16 * 72]; // per-wave [16][72] 18 KB
    const int tid = threadIdx.x;
    const int win = blockIdx.x;
    const int b = win >> 6, wrw = win & 63;
    const int wy = wrw >> 3, wx = wrw & 7;
    const size_t wbase = (size_t)b * HWP + (size_t)(wy * 7) * WW + wx * 7;

    {
        const int m = tid & 63;
        const int mq = div7(m), mr = m - mq * 7;
        const unsigned short* vrow = qkv + (wbase + mq * WW + mr) * NQKV + 512;
        for (int R = tid >> 6; R < 256; R += 8)
            VT[R * 72 + m] = (m < 49) ? (short)vrow[R] : (short)0;
    }

    const int lane = tid & 63;
    const int h = tid >> 6;
    const int c = lane & 15, qg = lane >> 4;

    short8 aq[4], bk[4];
    #pragma unroll
    for (int f = 0; f < 4; ++f) {
        int t = f * 16 + c; if (t > 48) t = 48;
        const int tq = div7(t), tr = t - tq * 7;
        const unsigned short* base = qkv + (wbase + tq * WW + tr) * NQKV + h * 32 + qg * 8;
        aq[f] = *(const short8*)base;
        bk[f] = *(const short8*)(base + 256);
    }
    __syncthreads();

    short8 bv[2][2];
    #pragma unroll
    for (int ks = 0; ks < 2; ++ks)
        #pragma unroll
        for (int fo = 0; fo < 2; ++fo)
            bv[ks][fo] = *(const short8*)&VT[(h * 32 + fo * 16 + c) * 72 + ks * 32 + qg * 8];

    const float scale = 0.17677669529663687f;
    short* pw = PL + h * 16 * 72;

    #pragma unroll
    for (int fm = 0; fm < 4; ++fm) {
        f32x4 s[4];
        #pragma unroll
        for (int fj = 0; fj < 4; ++fj)
            s[fj] = __builtin_amdgcn_mfma_f32_16x16x32_bf16(aq[fm], bk[fj],
                                                            (f32x4){0.f,0.f,0.f,0.f}, 0, 0, 0);
        float p[4][4];
        #pragma unroll
        for (int reg = 0; reg < 4; ++reg) {
            int n = fm * 16 + qg * 4 + reg; int nc = n > 48 ? 48 : n;
            int nd = div7(nc), nm = nc - nd * 7;
            #pragma unroll
            for (int fj = 0; fj < 4; ++fj) {
                int mm = fj * 16 + c;
                float bias;
                if (mm < 49) {
                    int md = div7(mm), mmod = mm - md * 7;
                    int idx = (nd - md + 6) * 13 + (nm - mmod + 6);
                    bias = rpb[idx * NHEADS + h];
                } else bias = -1e30f;
                p[fj][reg] = s[fj][reg] * scale + bias;
            }
        }
        float inv[4];
        #pragma unroll
        for (int reg = 0; reg < 4; ++reg) {
            float mx = fmaxf(fmaxf(p[0][reg], p[1][reg]), fmaxf(p[2][reg], p[3][reg]));
            mx = fmaxf(mx, __shfl_xor(mx, 1));
            mx = fmaxf(mx, __shfl_xor(mx, 2));
            mx = fmaxf(mx, __shfl_xor(mx, 4));
            mx = fmaxf(mx, __shfl_xor(mx, 8));
            float sum = 0.f;
            #pragma unroll
            for (int fj = 0; fj < 4; ++fj) {
                float e = __expf(p[fj][reg] - mx);
                p[fj][reg] = e; sum += e;
            }
            sum += __shfl_xor(sum, 1);
            sum += __shfl_xor(sum, 2);
            sum += __shfl_xor(sum, 4);
            sum += __shfl_xor(sum, 8);
            inv[reg] = 1.0f / sum;
        }
        #pragma unroll
        for (int fj = 0; fj < 4; ++fj)
            #pragma unroll
            for (int reg = 0; reg < 4; ++reg) {
                float v = p[fj][reg] * inv[reg];
                float o = __shfl_xor(v, 1);
                unsigned packed = (c & 1) ? pack2bf(o, v) : pack2bf(v, o);
                if ((c & 1) == 0)
                    *(unsigned*)&pw[(qg * 4 + reg) * 72 + fj * 16 + c] = packed;
            }
        short8 ap0 = *(const short8*)&pw[c * 72 + 0 * 32 + qg * 8];
        short8 ap1 = *(const short8*)&pw[c * 72 + 1 * 32 + qg * 8];
        #pragma unroll
        for (int fo = 0; fo < 2; ++fo) {
            f32x4 o4 = __builtin_amdgcn_mfma_f32_16x16x32_bf16(ap0, bv[0][fo],
                                                               (f32x4){0.f,0.f,0.f,0.f}, 0, 0, 0);
            o4 = __builtin_amdgcn_mfma_f32_16x16x32_bf16(ap1, bv[1][fo], o4, 0, 0, 0);
            #pragma unroll
            for (int reg = 0; reg < 4; ++reg) {
                int n = fm * 16 + qg * 4 + reg;
                if (n < 49) {
                    int nd = div7(n), nm = n - nd * 7;
                    obuf[(wbase + nd * WW + nm) * DIM + h * 32 + fo * 16 + c] =
                        (unsigned short)f2bf(o4[reg]);
                }
            }
        }
    }
}

// ---------------------------------------------------------------------------
// Kernel E (MFMA): out[b,c,p] += rate1 * (obuf @ proj_w^T + pb)
__global__ __launch_bounds__(256) void proj_gemm(const unsigned short* __restrict__ obuf,
                                                 const unsigned short* __restrict__ pwb,
                                                 const float* __restrict__ pb,
                                                 const float* __restrict__ rate1p,
                                                 float* __restrict__ out) {
    __shared__ short M_lds[128 * 64];
    __shared__ short C_lds[128 * 64];
    const int bidx = blockIdx.x;
    const int wg = (bidx & 7) * 98 + (bidx >> 3);   // grid 784 = 8*98
    const int ct = wg & 1, mt = wg >> 1;
    const int m0 = mt * 128, c0 = ct * 128;

    const int tid = threadIdx.x;
    const int lane = tid & 63;
    const int wave = tid >> 6;
    const int wr = wave >> 1, wc = wave & 1;

    const int srow = tid & 127;
    const int kh = tid >> 7;
    const unsigned short* mptr = obuf + (size_t)(m0 + srow) * DIM + kh * 32;
    const unsigned short* cptr = pwb  + (size_t)(c0 + srow) * DIM + kh * 32;

    f32x4 acc[4][4];
    #pragma unroll
    for (int i = 0; i < 4; ++i)
        #pragma unroll
        for (int j = 0; j < 4; ++j) acc[i][j] = (f32x4){0.f, 0.f, 0.f, 0.f};

    const int r = lane & 15, q = lane >> 4;
    for (int k0 = 0; k0 < DIM; k0 += 64) {
        __syncthreads();
        #pragma unroll
        for (int g = 0; g < 4; ++g) {
            *(short8*)&M_lds[srow * 64 + 8 * ((kh * 4 + g) ^ (srow & 7))] =
                *(const short8*)(mptr + k0 + g * 8);
            *(short8*)&C_lds[srow * 64 + 8 * ((kh * 4 + g) ^ (srow & 7))] =
                *(const short8*)(cptr + k0 + g * 8);
        }
        __syncthreads();
        #pragma unroll
        for (int ks = 0; ks < 2; ++ks) {
            short8 cf[4], mf[4];
            #pragma unroll
            for (int f = 0; f < 4; ++f) {
                int crow = wr * 64 + f * 16 + r;
                cf[f] = *(const short8*)&C_lds[crow * 64 + 8 * ((ks * 4 + q) ^ (crow & 7))];
                int mrow = wc * 64 + f * 16 + r;
                mf[f] = *(const short8*)&M_lds[mrow * 64 + 8 * ((ks * 4 + q) ^ (mrow & 7))];
            }
            #pragma unroll
            for (int fc = 0; fc < 4; ++fc)
                #pragma unroll
                for (int fm2 = 0; fm2 < 4; ++fm2)
                    acc[fc][fm2] = __builtin_amdgcn_mfma_f32_16x16x32_bf16(
                        cf[fc], mf[fm2], acc[fc][fm2], 0, 0, 0);
        }
    }
    const float r1 = rate1p[0];
    size_t boff[4];
    #pragma unroll
    for (int fm2 = 0; fm2 < 4; ++fm2) {
        int mb = m0 + wc * 64 + fm2 * 16 + r;
        boff[fm2] = (size_t)(mb / HWP) * DIM * HWP + (mb % HWP);
    }
    #pragma unroll
    for (int fc = 0; fc < 4; ++fc) {
        #pragma unroll
        for (int reg = 0; reg < 4; ++reg) {
            const int cc = c0 + wr * 64 + fc * 16 + q * 4 + reg;
            const float bias = pb[cc];
            #pragma unroll
            for (int fm2 = 0; fm2 < 4; ++fm2) {
                float* dst = out + boff[fm2] + (size_t)cc * HWP;
                *dst = *dst + r1 * (acc[fc][fm2][reg] + bias);
            }
        }
    }
}

// ---------------------------------------------------------------------------
extern "C" void kernel_launch(void* const* d_in, const int* in_sizes, int n_in,
                              void* d_out, int out_size, void* d_ws, size_t ws_size,
                              hipStream_t stream) {
    const float* x      = (const float*)d_in[0];
    const float* qkv_w  = (const float*)d_in[1];
    const float* qkv_b  = (const float*)d_in[2];
    const float* fc_w   = (const float*)d_in[3];
    const float* fc_b   = (const float*)d_in[4];
    const float* dep_w  = (const float*)d_in[5];
    const float* proj_w = (const float*)d_in[6];
    const float* proj_b = (const float*)d_in[7];
    const float* rpb    = (const float*)d_in[8];
    const float* rate1  = (const float*)d_in[9];
    const float* rate2  = (const float*)d_in[10];
    float* out = (float*)d_out;

    unsigned short* qkv   = (unsigned short*)d_ws;
    unsigned short* xt    = (unsigned short*)((char*)d_ws + XT_OFF);
    unsigned short* wqt   = (unsigned short*)((char*)d_ws + WQT_OFF);
    unsigned short* pwb   = (unsigned short*)((char*)d_ws + PWB_OFF);
    unsigned short* fconv = (unsigned short*)((char*)d_ws + FCONV_OFF);
    unsigned short* obuf  = fconv;  // reused after conv_kernel consumes fconv

    xpose_kernel<<<dim3(7, 4, BATCH), 256, 0, stream>>>(x, xt);
    prep_kernel<<<dim3(64), 256, 0, stream>>>(qkv_w, proj_w, wqt, pwb);
    qkv_gemm<<<dim3(2352), 256, 0, stream>>>(xt, wqt, qkv_b, qkv);
    fc_kernel<<<dim3(HWP / 16, BATCH), 256, 0, stream>>>(qkv, fc_w, fc_b, fconv);
    conv_kernel<<<dim3(7, 32, BATCH), 256, 0, stream>>>(fconv, dep_w, rate2, out);
    attn_kernel<<<dim3(1024), 512, 0, stream>>>(qkv, rpb, obuf);
    proj_gemm<<<dim3(784), 256, 0, stream>>>(obuf, pwb, proj_b, rate1, out);
}